// Round 4
// baseline (465.163 us; speedup 1.0000x reference)
//
#include <hip/hip_runtime.h>

#define D 128
#define LSTR 132   // padded LDS row stride (floats)
#define CAP 3072   // LDS edge capacity per 32-row tile (avg ~512)
#define NBLK 256   // fixed hist/fill block count (G columns)

typedef __attribute__((ext_vector_type(8))) short short8;
typedef __attribute__((ext_vector_type(4))) float f32x4;

static __device__ __forceinline__ unsigned short f2bf(float f) {
    unsigned u = __float_as_uint(f);
    return (unsigned short)((u + 0x7fffu + ((u >> 16) & 1u)) >> 16);  // RNE
}

// ---------------------------------------------------------------------------
// GraphSAGE (mean) x2 + head. bf16 features (fp32 accumulate).
// Prep = round-0 proven chain (no global-atomic RMW):
//   prep+histA: cast x->bf16 (float4/thread), transpose weights; LDS
//     histogram over 32-row tiles -> G[bin][blk]
//   scanB: one wave per bin, coalesced uint4 scan over 256 columns
//   scanC: single-block scan of bin totals -> tile_base[]
//   fillB: LDS rank replay -> csr[...] = src | dst<<16 (tile-grouped)
//   sortT: one block per tile, in-LDS 32-bin counting sort -> row-sorted csr
//          + invL_g[N] = 1/max(deg,1)   [runs ONCE, reused 2x]
// sage: wide-load gather (16 lanes/edge x dwordx4, 32-edge batches,
//   1-deep SW pipeline, __launch_bounds__(256,2) to license VGPR/MLP)
//   -> segmented fp32 accumulate -> MFMA dual GEMM (mean at A-frag build).
// d_ws: tot[2048] | tile_base[2052] | invL_g[Npad] | G[2048*NBLK] | csr[Epad]
//       | xb bf16[N*D] | hb bf16[N*D] | Bt1 bf16[128*256] | Bt2 bf16[128*256]
// ---------------------------------------------------------------------------

// Blocks [0, NBLK): LDS histogram of dst tiles. Blocks [NBLK, ...): prep.
__global__ __launch_bounds__(256) void prep_hist_kernel(
    const float* __restrict__ x, const float* __restrict__ W1l,
    const float* __restrict__ W1r, const float* __restrict__ W2l,
    const float* __restrict__ W2r, uint2* __restrict__ xb4,
    unsigned short* __restrict__ Bt1, unsigned short* __restrict__ Bt2,
    int NX4, const int* __restrict__ dst, int E, int nbins,
    unsigned* __restrict__ G) {
    const int t = threadIdx.x;
    if (blockIdx.x < NBLK) {
        __shared__ int h[2048];
        for (int i = t; i < nbins; i += 256) h[i] = 0;
        __syncthreads();
        const int per = (E + NBLK - 1) / NBLK;
        const int lo = blockIdx.x * per;
        const int hi = min(lo + per, E);
        for (int i = lo + t; i < hi; i += 256) atomicAdd(&h[dst[i] >> 5], 1);
        __syncthreads();
        for (int i = t; i < nbins; i += 256)
            G[(size_t)i * NBLK + blockIdx.x] = (unsigned)h[i];
        return;
    }
    const int i = (blockIdx.x - NBLK) * 256 + t;
    if (i < NX4) {
        const float4 v = *(const float4*)(x + 4 * (size_t)i);
        uint2 o;
        o.x = (unsigned)f2bf(v.x) | ((unsigned)f2bf(v.y) << 16);
        o.y = (unsigned)f2bf(v.z) | ((unsigned)f2bf(v.w) << 16);
        xb4[i] = o;
    } else if (i < NX4 + 2 * 32768) {
        const int j = i - NX4;
        const int which = j >> 15;  // 0 -> layer1, 1 -> layer2
        const int jj = j & 32767;
        const int n = jj >> 8;
        const int k = jj & 255;
        const float* Wl = which ? W2l : W1l;
        const float* Wr = which ? W2r : W1r;
        const float w = (k < 128) ? Wl[k * 128 + n] : Wr[(k - 128) * 128 + n];
        (which ? Bt2 : Bt1)[jj] = f2bf(w);
    }
}

// One wave per bin: coalesced uint4 exclusive scan over the 256 columns.
__global__ __launch_bounds__(256) void scanB_kernel(unsigned* __restrict__ G,
                                                    int nbins,
                                                    int* __restrict__ tot) {
    const int wave = threadIdx.x >> 6;
    const int lane = threadIdx.x & 63;
    const int bin = blockIdx.x * 4 + wave;
    if (bin >= nbins) return;
    unsigned* p = G + (size_t)bin * NBLK + lane * 4;
    uint4 v = *(uint4*)p;
    const unsigned s = v.x + v.y + v.z + v.w;
    unsigned sc = s;
#pragma unroll
    for (int off = 1; off < 64; off <<= 1) {
        const unsigned u = (unsigned)__shfl_up((int)sc, off, 64);
        if (lane >= off) sc += u;
    }
    const unsigned excl = sc - s;
    uint4 w;
    w.x = excl;
    w.y = excl + v.x;
    w.z = excl + v.x + v.y;
    w.w = excl + v.x + v.y + v.z;
    *(uint4*)p = w;
    if (lane == 63) tot[bin] = (int)(excl + s);
}

// Single-block exclusive scan of tot -> tile_base[0..nbins].
__global__ __launch_bounds__(1024) void scanC_kernel(
    const int* __restrict__ tot, int nbins, int* __restrict__ tile_base) {
    __shared__ int part[1024];
    const int t = threadIdx.x;
    const int chunk = (nbins + 1023) >> 10;
    const int lo = min(t * chunk, nbins);
    const int hi = min(lo + chunk, nbins);
    int s = 0;
    for (int i = lo; i < hi; ++i) s += tot[i];
    part[t] = s;
    __syncthreads();
    for (int off = 1; off < 1024; off <<= 1) {
        int add = (t >= off) ? part[t - off] : 0;
        __syncthreads();
        part[t] += add;
        __syncthreads();
    }
    int excl = (t == 0) ? 0 : part[t - 1];
    for (int i = lo; i < hi; ++i) {
        tile_base[i] = excl;
        excl += tot[i];
    }
    if (t == 1023) tile_base[nbins] = part[1023];
}

// Rank replay + scatter into tile-grouped csr.
__global__ __launch_bounds__(256) void fillB_kernel(
    const int* __restrict__ src, const int* __restrict__ dst, int E,
    const unsigned* __restrict__ G, const int* __restrict__ tile_base,
    unsigned* __restrict__ csr, int nbins) {
    __shared__ int rank[2048];
    __shared__ int base[2048];
    const int t = threadIdx.x;
    for (int i = t; i < nbins; i += 256) {
        rank[i] = 0;
        base[i] = tile_base[i] + (int)G[(size_t)i * NBLK + blockIdx.x];
    }
    __syncthreads();
    const int per = (E + NBLK - 1) / NBLK;
    const int lo = blockIdx.x * per;
    const int hi = min(lo + per, E);
    for (int i = lo + t; i < hi; i += 256) {
        const int d = dst[i];
        const int bin = d >> 5;
        const int r = atomicAdd(&rank[bin], 1);
        csr[base[bin] + r] = (unsigned)src[i] | ((unsigned)d << 16);
    }
}

// One block per tile: in-LDS 32-bin counting sort of the tile's csr range
// (row-grouped, in place) + invL_g = 1/max(deg,1). Runs once, reused by both
// sage layers. nE > CAP (never at E/nbins ~512): skip reorder, still correct.
__global__ __launch_bounds__(256) void sortT_kernel(unsigned* __restrict__ csr,
                                                    const int* __restrict__
                                                        tile_base,
                                                    float* __restrict__ invL_g,
                                                    int N) {
    __shared__ unsigned sortedE[CAP];
    __shared__ int rowcnt[32];
    __shared__ int rowofs[32];
    const int b = blockIdx.x;
    const int i0 = b * 32;
    const int t = threadIdx.x;
    const int rs0 = tile_base[b];
    const int re0 = tile_base[b + 1];
    const int nE = re0 - rs0;

    if (t < 32) rowcnt[t] = 0;
    __syncthreads();
    for (int i = t; i < nE; i += 256)
        atomicAdd(&rowcnt[(csr[rs0 + i] >> 16) & 31], 1);
    __syncthreads();
    if (t < 32) {
        const int v = rowcnt[t];
        if (i0 + t < N) invL_g[i0 + t] = 1.0f / fmaxf((float)v, 1.0f);
        int s = v;
#pragma unroll
        for (int off = 1; off < 32; off <<= 1) {
            const int u = __shfl_up(s, off, 32);
            if ((t & 31) >= off) s += u;
        }
        rowofs[t] = s - v;
    }
    __syncthreads();
    if (nE <= CAP) {
        for (int i = t; i < nE; i += 256) {
            const unsigned p = csr[rs0 + i];
            const int k = atomicAdd(&rowofs[(p >> 16) & 31], 1);
            sortedE[k] = p;
        }
        __syncthreads();
        for (int i = t; i < nE; i += 256) csr[rs0 + i] = sortedE[i];
    }
}

// Fused: wide-load segmented gather (16 lanes/edge x 16B, 32-edge batches,
// 1-deep pipeline) -> fp32 acc into LDS -> MFMA dual GEMM with mean applied
// at A-frag build. HEAD folds the Linear(128,1).
template <bool HEAD>
__global__ __launch_bounds__(256, 2) void sage_kernel(
    const unsigned short* __restrict__ xb, const unsigned* __restrict__ csr,
    const int* __restrict__ tile_base, const float* __restrict__ invL_g,
    const unsigned short* __restrict__ Bt,  // [128 n][256 k] bf16
    const float* __restrict__ bl, const float* __restrict__ Wout,
    const float* __restrict__ bout, unsigned short* __restrict__ hb_out,
    float* __restrict__ out, int N) {
    __shared__ float aggL[32 * LSTR];
    __shared__ float invL[32];
    __shared__ float redH[64];

    const int b = blockIdx.x;
    const int i0 = b * 32;
    const int t = threadIdx.x;
    const int wv = t >> 6;
    const int lane = t & 63;
    const int sub = lane >> 4;  // sub-slot: which of 4 edges per load instr
    const int cl = lane & 15;   // 16B chunk within the 256B row
    const int c8 = cl << 3;     // channel base (8 bf16)

    for (int i = t; i < 32 * LSTR; i += 256) aggL[i] = 0.f;
    if (t < 32) invL[t] = (i0 + t < N) ? invL_g[i0 + t] : 1.0f;
    __syncthreads();

    // ---- wide-load segmented gather over row-sorted csr ----
    const int rs0 = tile_base[b];
    const int re0 = tile_base[b + 1];
    const int nE = re0 - rs0;
    const int ws_ = rs0 + ((nE * wv) >> 2);
    const int we_ = rs0 + ((nE * (wv + 1)) >> 2);
    const int cnt = we_ - ws_;
    const int lastc = re0 - 1;

    float a[8];
#pragma unroll
    for (int j = 0; j < 8; ++j) a[j] = 0.f;
    int cur = -1;

    if (cnt > 0) {
        const int nb = (cnt + 31) >> 5;
        unsigned dc[8];
        uint4 vc[8];
        {
            const int e0 = ws_ + sub;
#pragma unroll
            for (int j = 0; j < 8; ++j) dc[j] = csr[min(e0 + 4 * j, lastc)];
#pragma unroll
            for (int j = 0; j < 8; ++j)
                vc[j] =
                    *(const uint4*)(xb + (size_t)(dc[j] & 0xffffu) * D + c8);
        }
        for (int k = 0; k < nb; ++k) {
            unsigned dn[8];
            uint4 vn[8];
            const bool more = (k + 1 < nb);
            if (more) {
                const int e1 = ws_ + (k + 1) * 32 + sub;
#pragma unroll
                for (int j = 0; j < 8; ++j) dn[j] = csr[min(e1 + 4 * j, lastc)];
#pragma unroll
                for (int j = 0; j < 8; ++j)
                    vn[j] = *(const uint4*)(xb +
                                            (size_t)(dn[j] & 0xffffu) * D + c8);
            }
            const int e0 = ws_ + k * 32 + sub;
#pragma unroll
            for (int j = 0; j < 8; ++j) {
                if (e0 + 4 * j < we_) {
                    const int r = (int)(dc[j] >> 16) - i0;
                    if (r != cur) {
                        if (cur >= 0) {
                            float* q = aggL + cur * LSTR + c8;
#pragma unroll
                            for (int m = 0; m < 8; ++m) atomicAdd(q + m, a[m]);
#pragma unroll
                            for (int m = 0; m < 8; ++m) a[m] = 0.f;
                        }
                        cur = r;
                    }
                    const uint4 u = vc[j];
                    a[0] += __uint_as_float(u.x << 16);
                    a[1] += __uint_as_float(u.x & 0xffff0000u);
                    a[2] += __uint_as_float(u.y << 16);
                    a[3] += __uint_as_float(u.y & 0xffff0000u);
                    a[4] += __uint_as_float(u.z << 16);
                    a[5] += __uint_as_float(u.z & 0xffff0000u);
                    a[6] += __uint_as_float(u.w << 16);
                    a[7] += __uint_as_float(u.w & 0xffff0000u);
                }
            }
            if (more) {
#pragma unroll
                for (int j = 0; j < 8; ++j) {
                    dc[j] = dn[j];
                    vc[j] = vn[j];
                }
            }
        }
        if (cur >= 0) {
            float* q = aggL + cur * LSTR + c8;
#pragma unroll
            for (int m = 0; m < 8; ++m) atomicAdd(q + m, a[m]);
        }
    }
    __syncthreads();

    // ---- MFMA dual GEMM: [agg*inv | x](32x256) @ Bt^T(256x128) ----
    const int ln = lane & 15;
    const int quad = lane >> 4;
    const int mtile = wv & 1;       // rows mtile*16..+15
    const int nt0 = (wv >> 1) * 4;  // 4 n-tiles per wave
    const int mrow = mtile * 16 + ln;
    const int gmr = i0 + mrow;
    const float inv = invL[mrow];

    f32x4 acc4[4] = {f32x4{0.f, 0.f, 0.f, 0.f}, f32x4{0.f, 0.f, 0.f, 0.f},
                     f32x4{0.f, 0.f, 0.f, 0.f}, f32x4{0.f, 0.f, 0.f, 0.f}};

#pragma unroll
    for (int s = 0; s < 4; ++s) {
        const int kb = s * 32 + quad * 8;
        const float* ap = aggL + mrow * LSTR + kb;
        const float4 fa = *(const float4*)ap;
        const float4 fb = *(const float4*)(ap + 4);
        const short8 aA = {(short)f2bf(fa.x * inv), (short)f2bf(fa.y * inv),
                           (short)f2bf(fa.z * inv), (short)f2bf(fa.w * inv),
                           (short)f2bf(fb.x * inv), (short)f2bf(fb.y * inv),
                           (short)f2bf(fb.z * inv), (short)f2bf(fb.w * inv)};
        short8 aX = {0, 0, 0, 0, 0, 0, 0, 0};
        if (gmr < N) aX = *(const short8*)(xb + (size_t)gmr * D + kb);
#pragma unroll
        for (int nt = 0; nt < 4; ++nt) {
            const int n = (nt0 + nt) * 16 + ln;
            const short8 b1 = *(const short8*)(Bt + n * 256 + kb);
            const short8 b2 = *(const short8*)(Bt + n * 256 + 128 + kb);
            acc4[nt] = __builtin_amdgcn_mfma_f32_16x16x32_bf16(aA, b1, acc4[nt],
                                                               0, 0, 0);
            acc4[nt] = __builtin_amdgcn_mfma_f32_16x16x32_bf16(aX, b2, acc4[nt],
                                                               0, 0, 0);
        }
    }

    // ---- epilogue: C/D layout col=lane&15, row=quad*4+reg ----
    float biasv[4], woutv[4];
#pragma unroll
    for (int nt = 0; nt < 4; ++nt) {
        const int col = (nt0 + nt) * 16 + ln;
        biasv[nt] = bl[col];
        if (HEAD) woutv[nt] = Wout[col];
    }

    if (!HEAD) {
#pragma unroll
        for (int r = 0; r < 4; ++r) {
            const int gr = i0 + mtile * 16 + quad * 4 + r;
            if (gr < N) {
#pragma unroll
                for (int nt = 0; nt < 4; ++nt) {
                    const int col = (nt0 + nt) * 16 + ln;
                    const float v = fmaxf(acc4[nt][r] + biasv[nt], 0.f);
                    hb_out[(size_t)gr * D + col] = f2bf(v);
                }
            }
        }
    } else {
        const float b0 = bout[0];
#pragma unroll
        for (int r = 0; r < 4; ++r) {
            const int row = mtile * 16 + quad * 4 + r;
            float p = 0.f;
#pragma unroll
            for (int nt = 0; nt < 4; ++nt) {
                const float v = fmaxf(acc4[nt][r] + biasv[nt], 0.f);
                p += v * woutv[nt];
            }
            p += __shfl_xor(p, 1);
            p += __shfl_xor(p, 2);
            p += __shfl_xor(p, 4);
            p += __shfl_xor(p, 8);
            if (ln == 0) redH[row * 2 + (wv >> 1)] = p;
        }
        __syncthreads();
        if (t < 32) {
            const int gr = i0 + t;
            if (gr < N) out[gr] = redH[t * 2] + redH[t * 2 + 1] + b0;
        }
    }
}

extern "C" void kernel_launch(void* const* d_in, const int* in_sizes, int n_in,
                              void* d_out, int out_size, void* d_ws,
                              size_t ws_size, hipStream_t stream) {
    const float* x = (const float*)d_in[0];
    const int* ei = (const int*)d_in[1];
    const float* W1l = (const float*)d_in[2];
    const float* b1l = (const float*)d_in[3];
    const float* W1r = (const float*)d_in[4];
    const float* W2l = (const float*)d_in[5];
    const float* b2l = (const float*)d_in[6];
    const float* W2r = (const float*)d_in[7];
    const float* Wout = (const float*)d_in[8];
    const float* bout = (const float*)d_in[9];

    const int N = in_sizes[0] / D;
    const int E = in_sizes[1] / 2;
    const int* src = ei;
    const int* dst = ei + E;

    const int nbins = (N + 31) / 32;  // 32-row tiles (= sage blocks), <= 2048
    const size_t Npad = (size_t)((N + 255) & ~255);
    const size_t Epad = (size_t)((E + 255) & ~255);

    int* tot = (int*)d_ws;                        // [2048]
    int* tile_base = tot + 2048;                  // [2052]
    float* invL_g = (float*)(tile_base + 2052);   // [Npad]
    unsigned* G = (unsigned*)(invL_g + Npad);     // [2048 * NBLK]
    unsigned* csr = G + (size_t)2048 * NBLK;
    unsigned short* xb = (unsigned short*)(csr + Epad);
    unsigned short* hb = xb + (size_t)N * D;
    unsigned short* Bt1 = hb + (size_t)N * D;
    unsigned short* Bt2 = Bt1 + 128 * 256;
    float* out = (float*)d_out;

    const int NX4 = N * D / 4;
    const int prep_blocks = (NX4 + 2 * 32768 + 255) / 256;

    prep_hist_kernel<<<NBLK + prep_blocks, 256, 0, stream>>>(
        x, W1l, W1r, W2l, W2r, (uint2*)xb, Bt1, Bt2, NX4, dst, E, nbins, G);
    scanB_kernel<<<(nbins + 3) / 4, 256, 0, stream>>>(G, nbins, tot);
    scanC_kernel<<<1, 1024, 0, stream>>>(tot, nbins, tile_base);
    fillB_kernel<<<NBLK, 256, 0, stream>>>(src, dst, E, G, tile_base, csr,
                                           nbins);
    sortT_kernel<<<nbins, 256, 0, stream>>>(csr, tile_base, invL_g, N);

    sage_kernel<false><<<nbins, 256, 0, stream>>>(
        xb, csr, tile_base, invL_g, Bt1, b1l, nullptr, nullptr, hb, nullptr, N);
    sage_kernel<true><<<nbins, 256, 0, stream>>>(
        hb, csr, tile_base, invL_g, Bt2, b2l, Wout, bout, nullptr, out, N);
}

// Round 5
// 379.229 us; speedup vs baseline: 1.2266x; 1.2266x over previous
//
#include <hip/hip_runtime.h>

#define D 128
#define LSTR 132   // padded LDS row stride (floats)
#define CAP 3072   // LDS descriptor capacity per 32-row tile (avg ~512)
#define NBLK 256   // hist block count

typedef __attribute__((ext_vector_type(8))) short short8;
typedef __attribute__((ext_vector_type(4))) float f32x4;

static __device__ __forceinline__ unsigned short f2bf(float f) {
    unsigned u = __float_as_uint(f);
    return (unsigned short)((u + 0x7fffu + ((u >> 16) & 1u)) >> 16);  // RNE
}

// ---------------------------------------------------------------------------
// GraphSAGE (mean) x2 + head. bf16 features (fp32 accumulate).
// Prep (4 kernels, no G matrix):
//   P1 prep+hist: cast x->bf16 (float4/thread), transpose weights; LDS tile
//      histogram -> atomicAdd into global tot[nbins]
//   P2 scanC: single-block scan of tot -> tile_base[] and cursor[] init
//   P3 fill: pos = atomicAdd(&cursor[dst>>5]) -> csr[pos] = src | dst<<16
//      (tile-grouped, unsorted within tile)
//   P4 sortT: per-tile in-LDS 32-bin counting sort -> row-sorted csr +
//      invL_g[N] = 1/max(deg,1)   [runs ONCE, reused by both layers]
// sage (512 threads): tile csr staged to LDS (descriptor reads leave the
//   vmem stream -> feature loads are the only vmcnt ops), 16 gather groups
//   of 32 lanes, R0-proven 8-wide batches -> segmented fp32 accumulate ->
//   MFMA dual GEMM (mean at A-frag build). HEAD folds the Linear(128,1).
// d_ws: tot[2048] | tile_base[2052] | cursor[2048] | invL_g[Npad] | csr[Epad]
//       | xb bf16[N*D] | hb bf16[N*D] | Bt1 bf16[128*256] | Bt2 bf16[128*256]
// ---------------------------------------------------------------------------

// Blocks [0, NBLK): LDS histogram of dst tiles -> global tot. Rest: prep.
__global__ __launch_bounds__(256) void prep_hist_kernel(
    const float* __restrict__ x, const float* __restrict__ W1l,
    const float* __restrict__ W1r, const float* __restrict__ W2l,
    const float* __restrict__ W2r, uint2* __restrict__ xb4,
    unsigned short* __restrict__ Bt1, unsigned short* __restrict__ Bt2,
    int NX4, const int* __restrict__ dst, int E, int nbins,
    int* __restrict__ tot) {
    const int t = threadIdx.x;
    if (blockIdx.x < NBLK) {
        __shared__ int h[2048];
        for (int i = t; i < 2048; i += 256) h[i] = 0;
        __syncthreads();
        const int per = (E + NBLK - 1) / NBLK;
        const int lo = blockIdx.x * per;
        const int hi = min(lo + per, E);
        for (int i = lo + t; i < hi; i += 256) atomicAdd(&h[dst[i] >> 5], 1);
        __syncthreads();
        for (int i = t; i < nbins; i += 256) {
            const int v = h[i];
            if (v) atomicAdd(&tot[i], v);
        }
        return;
    }
    const int i = (blockIdx.x - NBLK) * 256 + t;
    if (i < NX4) {
        const float4 v = *(const float4*)(x + 4 * (size_t)i);
        uint2 o;
        o.x = (unsigned)f2bf(v.x) | ((unsigned)f2bf(v.y) << 16);
        o.y = (unsigned)f2bf(v.z) | ((unsigned)f2bf(v.w) << 16);
        xb4[i] = o;
    } else if (i < NX4 + 2 * 32768) {
        const int j = i - NX4;
        const int which = j >> 15;  // 0 -> layer1, 1 -> layer2
        const int jj = j & 32767;
        const int n = jj >> 8;
        const int k = jj & 255;
        const float* Wl = which ? W2l : W1l;
        const float* Wr = which ? W2r : W1r;
        const float w = (k < 128) ? Wl[k * 128 + n] : Wr[(k - 128) * 128 + n];
        (which ? Bt2 : Bt1)[jj] = f2bf(w);
    }
}

// Single-block exclusive scan of tot -> tile_base[0..nbins] + cursor init.
__global__ __launch_bounds__(1024) void scanC_kernel(
    const int* __restrict__ tot, int nbins, int* __restrict__ tile_base,
    int* __restrict__ cursor) {
    __shared__ int part[1024];
    const int t = threadIdx.x;
    const int chunk = (nbins + 1023) >> 10;
    const int lo = min(t * chunk, nbins);
    const int hi = min(lo + chunk, nbins);
    int s = 0;
    for (int i = lo; i < hi; ++i) s += tot[i];
    part[t] = s;
    __syncthreads();
    for (int off = 1; off < 1024; off <<= 1) {
        int add = (t >= off) ? part[t - off] : 0;
        __syncthreads();
        part[t] += add;
        __syncthreads();
    }
    int excl = (t == 0) ? 0 : part[t - 1];
    for (int i = lo; i < hi; ++i) {
        tile_base[i] = excl;
        cursor[i] = excl;
        excl += tot[i];
    }
    if (t == 1023) tile_base[nbins] = part[1023];
}

// Scatter edges into tile-grouped csr via per-tile atomic rank.
__global__ __launch_bounds__(256) void fill_kernel(
    const int* __restrict__ src, const int* __restrict__ dst, int E,
    int* __restrict__ cursor, unsigned* __restrict__ csr) {
    const int i = blockIdx.x * 256 + threadIdx.x;
    if (i < E) {
        const int d = dst[i];
        const int pos = atomicAdd(&cursor[d >> 5], 1);
        csr[pos] = (unsigned)src[i] | ((unsigned)d << 16);
    }
}

// One block per tile: in-LDS 32-bin counting sort of the tile's csr range
// (row-grouped, in place) + invL_g = 1/max(deg,1). nE > CAP: skip reorder
// (still correct, sage handles unsorted via segmented atomics).
__global__ __launch_bounds__(256) void sortT_kernel(unsigned* __restrict__ csr,
                                                    const int* __restrict__
                                                        tile_base,
                                                    float* __restrict__ invL_g,
                                                    int N) {
    __shared__ unsigned sortedE[CAP];
    __shared__ int rowcnt[32];
    __shared__ int rowofs[32];
    const int b = blockIdx.x;
    const int i0 = b * 32;
    const int t = threadIdx.x;
    const int rs0 = tile_base[b];
    const int re0 = tile_base[b + 1];
    const int nE = re0 - rs0;

    if (t < 32) rowcnt[t] = 0;
    __syncthreads();
    for (int i = t; i < nE; i += 256)
        atomicAdd(&rowcnt[(csr[rs0 + i] >> 16) & 31], 1);
    __syncthreads();
    if (t < 32) {
        const int v = rowcnt[t];
        if (i0 + t < N) invL_g[i0 + t] = 1.0f / fmaxf((float)v, 1.0f);
        int s = v;
#pragma unroll
        for (int off = 1; off < 32; off <<= 1) {
            const int u = __shfl_up(s, off, 32);
            if ((t & 31) >= off) s += u;
        }
        rowofs[t] = s - v;
    }
    __syncthreads();
    if (nE <= CAP) {
        for (int i = t; i < nE; i += 256) {
            const unsigned p = csr[rs0 + i];
            const int k = atomicAdd(&rowofs[(p >> 16) & 31], 1);
            sortedE[k] = p;
        }
        __syncthreads();
        for (int i = t; i < nE; i += 256) csr[rs0 + i] = sortedE[i];
    }
}

// Fused: LDS-staged descriptors + segmented bf16 gather (fp32 acc into LDS)
// -> MFMA dual GEMM with mean applied at A-frag build. 512 threads.
template <bool HEAD>
__global__ __launch_bounds__(512) void sage_kernel(
    const unsigned short* __restrict__ xb, const unsigned* __restrict__ csr,
    const int* __restrict__ tile_base, const float* __restrict__ invL_g,
    const unsigned short* __restrict__ Bt,  // [128 n][256 k] bf16
    const float* __restrict__ bl, const float* __restrict__ Wout,
    const float* __restrict__ bout, unsigned short* __restrict__ hb_out,
    float* __restrict__ out, int N) {
    __shared__ float aggL[32 * LSTR];
    __shared__ unsigned csrL[CAP];
    __shared__ float invL[32];
    __shared__ float redH[128];

    const int b = blockIdx.x;
    const int i0 = b * 32;
    const int t = threadIdx.x;
    const int g = t >> 5;   // 16 gather groups
    const int l = t & 31;
    const int c4 = l << 2;  // 4 bf16 channels per lane

    const int rs0 = tile_base[b];
    const int re0 = tile_base[b + 1];
    const int nE = re0 - rs0;
    const int nS = min(nE, CAP);

    for (int i = t; i < 32 * LSTR; i += 512) aggL[i] = 0.f;
    if (t < 32) invL[t] = (i0 + t < N) ? invL_g[i0 + t] : 1.0f;
    // stage this tile's descriptors into LDS (coalesced, ~2KB)
    for (int i = t; i < nS; i += 512) csrL[i] = csr[rs0 + i];
    __syncthreads();

    // ---- segmented gather: descriptors from LDS, features from global ----
    int e = (nS * g) >> 4;
    const int ee = (nS * (g + 1)) >> 4;

    float4 acc = make_float4(0.f, 0.f, 0.f, 0.f);
    int cur = -1;

    auto ld = [&](unsigned p) -> uint2 {
        return *(const uint2*)(xb + (size_t)(p & 0xffffu) * D + c4);
    };
    auto step = [&](unsigned p, uint2 u) {
        const int r = (int)(p >> 16) - i0;
        if (r != cur) {
            if (cur >= 0) {
                float* q = aggL + cur * LSTR + c4;
                atomicAdd(q + 0, acc.x);
                atomicAdd(q + 1, acc.y);
                atomicAdd(q + 2, acc.z);
                atomicAdd(q + 3, acc.w);
            }
            acc = make_float4(0.f, 0.f, 0.f, 0.f);
            cur = r;
        }
        acc.x += __uint_as_float(u.x << 16);
        acc.y += __uint_as_float(u.x & 0xffff0000u);
        acc.z += __uint_as_float(u.y << 16);
        acc.w += __uint_as_float(u.y & 0xffff0000u);
    };

    while (e + 8 <= ee) {
        const unsigned p0 = csrL[e + 0], p1 = csrL[e + 1];
        const unsigned p2 = csrL[e + 2], p3 = csrL[e + 3];
        const unsigned p4 = csrL[e + 4], p5 = csrL[e + 5];
        const unsigned p6 = csrL[e + 6], p7 = csrL[e + 7];
        const uint2 v0 = ld(p0), v1 = ld(p1), v2 = ld(p2), v3 = ld(p3),
                    v4 = ld(p4), v5 = ld(p5), v6 = ld(p6), v7 = ld(p7);
        step(p0, v0); step(p1, v1); step(p2, v2); step(p3, v3);
        step(p4, v4); step(p5, v5); step(p6, v6); step(p7, v7);
        e += 8;
    }
    while (e < ee) {
        const unsigned p = csrL[e];
        step(p, ld(p));
        ++e;
    }
    if (nE > CAP) {  // rare overflow: per-edge from global (still correct)
        const int extra = nE - CAP;
        int e2 = CAP + ((extra * g) >> 4);
        const int ee2 = CAP + ((extra * (g + 1)) >> 4);
        for (; e2 < ee2; ++e2) {
            const unsigned p = csr[rs0 + e2];
            step(p, ld(p));
        }
    }
    if (cur >= 0) {
        float* q = aggL + cur * LSTR + c4;
        atomicAdd(q + 0, acc.x);
        atomicAdd(q + 1, acc.y);
        atomicAdd(q + 2, acc.z);
        atomicAdd(q + 3, acc.w);
    }
    __syncthreads();

    // ---- MFMA dual GEMM: [agg*inv | x](32x256) @ Bt^T(256x128) ----
    // 8 waves: wave = (mtile, pairsel); each wave does 2 n-tiles.
    const int wv = t >> 6;
    const int lane = t & 63;
    const int ln = lane & 15;
    const int quad = lane >> 4;
    const int mtile = wv & 1;        // rows mtile*16..+15
    const int nt0 = (wv >> 1) * 2;   // 2 n-tiles per wave
    const int mrow = mtile * 16 + ln;
    const int gmr = i0 + mrow;
    const float inv = invL[mrow];

    f32x4 acc4[2] = {f32x4{0.f, 0.f, 0.f, 0.f}, f32x4{0.f, 0.f, 0.f, 0.f}};

#pragma unroll
    for (int s = 0; s < 4; ++s) {
        const int kb = s * 32 + quad * 8;
        const float* ap = aggL + mrow * LSTR + kb;
        const float4 fa = *(const float4*)ap;
        const float4 fb = *(const float4*)(ap + 4);
        const short8 aA = {(short)f2bf(fa.x * inv), (short)f2bf(fa.y * inv),
                           (short)f2bf(fa.z * inv), (short)f2bf(fa.w * inv),
                           (short)f2bf(fb.x * inv), (short)f2bf(fb.y * inv),
                           (short)f2bf(fb.z * inv), (short)f2bf(fb.w * inv)};
        short8 aX = {0, 0, 0, 0, 0, 0, 0, 0};
        if (gmr < N) aX = *(const short8*)(xb + (size_t)gmr * D + kb);
#pragma unroll
        for (int nt = 0; nt < 2; ++nt) {
            const int n = (nt0 + nt) * 16 + ln;
            const short8 b1 = *(const short8*)(Bt + n * 256 + kb);
            const short8 b2 = *(const short8*)(Bt + n * 256 + 128 + kb);
            acc4[nt] = __builtin_amdgcn_mfma_f32_16x16x32_bf16(aA, b1, acc4[nt],
                                                               0, 0, 0);
            acc4[nt] = __builtin_amdgcn_mfma_f32_16x16x32_bf16(aX, b2, acc4[nt],
                                                               0, 0, 0);
        }
    }

    // ---- epilogue: C/D layout col=lane&15, row=quad*4+reg ----
    float biasv[2], woutv[2];
#pragma unroll
    for (int nt = 0; nt < 2; ++nt) {
        const int col = (nt0 + nt) * 16 + ln;
        biasv[nt] = bl[col];
        if (HEAD) woutv[nt] = Wout[col];
    }

    if (!HEAD) {
#pragma unroll
        for (int r = 0; r < 4; ++r) {
            const int gr = i0 + mtile * 16 + quad * 4 + r;
            if (gr < N) {
#pragma unroll
                for (int nt = 0; nt < 2; ++nt) {
                    const int col = (nt0 + nt) * 16 + ln;
                    const float v = fmaxf(acc4[nt][r] + biasv[nt], 0.f);
                    hb_out[(size_t)gr * D + col] = f2bf(v);
                }
            }
        }
    } else {
        const float b0 = bout[0];
#pragma unroll
        for (int r = 0; r < 4; ++r) {
            const int row = mtile * 16 + quad * 4 + r;
            float p = 0.f;
#pragma unroll
            for (int nt = 0; nt < 2; ++nt) {
                const float v = fmaxf(acc4[nt][r] + biasv[nt], 0.f);
                p += v * woutv[nt];
            }
            p += __shfl_xor(p, 1);
            p += __shfl_xor(p, 2);
            p += __shfl_xor(p, 4);
            p += __shfl_xor(p, 8);
            if (ln == 0) redH[row * 4 + (wv >> 1)] = p;
        }
        __syncthreads();
        if (t < 32) {
            const int gr = i0 + t;
            if (gr < N)
                out[gr] = redH[t * 4] + redH[t * 4 + 1] + redH[t * 4 + 2] +
                          redH[t * 4 + 3] + b0;
        }
    }
}

extern "C" void kernel_launch(void* const* d_in, const int* in_sizes, int n_in,
                              void* d_out, int out_size, void* d_ws,
                              size_t ws_size, hipStream_t stream) {
    const float* x = (const float*)d_in[0];
    const int* ei = (const int*)d_in[1];
    const float* W1l = (const float*)d_in[2];
    const float* b1l = (const float*)d_in[3];
    const float* W1r = (const float*)d_in[4];
    const float* W2l = (const float*)d_in[5];
    const float* b2l = (const float*)d_in[6];
    const float* W2r = (const float*)d_in[7];
    const float* Wout = (const float*)d_in[8];
    const float* bout = (const float*)d_in[9];

    const int N = in_sizes[0] / D;
    const int E = in_sizes[1] / 2;
    const int* src = ei;
    const int* dst = ei + E;

    const int nbins = (N + 31) / 32;  // 32-row tiles (= sage blocks), <= 2048
    const size_t Npad = (size_t)((N + 255) & ~255);
    const size_t Epad = (size_t)((E + 255) & ~255);

    int* tot = (int*)d_ws;                       // [2048]
    int* tile_base = tot + 2048;                 // [2052]
    int* cursor = tile_base + 2052;              // [2048]
    float* invL_g = (float*)(cursor + 2048);     // [Npad]
    unsigned* csr = (unsigned*)(invL_g + Npad);  // [Epad]
    unsigned short* xb = (unsigned short*)(csr + Epad);
    unsigned short* hb = xb + (size_t)N * D;
    unsigned short* Bt1 = hb + (size_t)N * D;
    unsigned short* Bt2 = Bt1 + 128 * 256;
    float* out = (float*)d_out;

    const int NX4 = N * D / 4;
    const int prep_blocks = (NX4 + 2 * 32768 + 255) / 256;

    hipMemsetAsync(tot, 0, 2048 * sizeof(int), stream);
    prep_hist_kernel<<<NBLK + prep_blocks, 256, 0, stream>>>(
        x, W1l, W1r, W2l, W2r, (uint2*)xb, Bt1, Bt2, NX4, dst, E, nbins, tot);
    scanC_kernel<<<1, 1024, 0, stream>>>(tot, nbins, tile_base, cursor);
    fill_kernel<<<(E + 255) / 256, 256, 0, stream>>>(src, dst, E, cursor, csr);
    sortT_kernel<<<nbins, 256, 0, stream>>>(csr, tile_base, invL_g, N);

    sage_kernel<false><<<nbins, 512, 0, stream>>>(
        xb, csr, tile_base, invL_g, Bt1, b1l, nullptr, nullptr, hb, nullptr, N);
    sage_kernel<true><<<nbins, 512, 0, stream>>>(
        hb, csr, tile_base, invL_g, Bt2, b2l, Wout, bout, nullptr, out, N);
}

// Round 6
// 267.379 us; speedup vs baseline: 1.7397x; 1.4183x over previous
//
#include <hip/hip_runtime.h>

#define D 128
#define LSTR 132   // padded LDS row stride (floats)
#define CAP 3072   // LDS edge capacity per 32-row tile (avg ~512)
#define NBLK 256   // fixed hist/fill block count (G columns)

typedef __attribute__((ext_vector_type(8))) short short8;
typedef __attribute__((ext_vector_type(4))) float f32x4;

static __device__ __forceinline__ unsigned short f2bf(float f) {
    unsigned u = __float_as_uint(f);
    return (unsigned short)((u + 0x7fffu + ((u >> 16) & 1u)) >> 16);  // RNE
}

// ---------------------------------------------------------------------------
// GraphSAGE (mean) x2 + head. bf16 features (fp32 accumulate).
// Prep = round-0 proven chain (LDS-sort, no global-atomic hot spots):
//   prep+histA: cast x->bf16 (float4/thread), transpose weights; LDS
//     histogram over 32-row tiles -> G[bin][blk]
//   scanB: one wave per bin, coalesced uint4 scan over 256 columns
//   scanC: single-block scan of bin totals -> tile_base[]
//   fillB: LDS rank replay -> csr[...] = src | dst<<16 (tile-grouped)
//   sortT: one block per tile, in-LDS 32-bin counting sort -> row-sorted csr
//          + invL_g[N] = 1/max(deg,1)   [runs ONCE, reused 2x]
// sage: segmented gather, R0 loop shape but 16-lane groups x uint4 (16B/lane)
//   -> one wave vmem instr covers 4 edge-rows (halved instruction count at
//   constant bytes; groups keep CONTIGUOUS edge ranges unlike R4).
//   -> fp32 acc in LDS -> MFMA dual GEMM (mean at A-frag build).
// d_ws: tot[2048] | tile_base[2052] | invL_g[Npad] | G[2048*NBLK] | csr[Epad]
//       | xb bf16[N*D] | hb bf16[N*D] | Bt1 bf16[128*256] | Bt2 bf16[128*256]
// ---------------------------------------------------------------------------

// Blocks [0, NBLK): LDS histogram of dst tiles. Blocks [NBLK, ...): prep.
__global__ __launch_bounds__(256) void prep_hist_kernel(
    const float* __restrict__ x, const float* __restrict__ W1l,
    const float* __restrict__ W1r, const float* __restrict__ W2l,
    const float* __restrict__ W2r, uint2* __restrict__ xb4,
    unsigned short* __restrict__ Bt1, unsigned short* __restrict__ Bt2,
    int NX4, const int* __restrict__ dst, int E, int nbins,
    unsigned* __restrict__ G) {
    const int t = threadIdx.x;
    if (blockIdx.x < NBLK) {
        __shared__ int h[2048];
        for (int i = t; i < nbins; i += 256) h[i] = 0;
        __syncthreads();
        const int per = (E + NBLK - 1) / NBLK;
        const int lo = blockIdx.x * per;
        const int hi = min(lo + per, E);
        for (int i = lo + t; i < hi; i += 256) atomicAdd(&h[dst[i] >> 5], 1);
        __syncthreads();
        for (int i = t; i < nbins; i += 256)
            G[(size_t)i * NBLK + blockIdx.x] = (unsigned)h[i];
        return;
    }
    const int i = (blockIdx.x - NBLK) * 256 + t;
    if (i < NX4) {
        const float4 v = *(const float4*)(x + 4 * (size_t)i);
        uint2 o;
        o.x = (unsigned)f2bf(v.x) | ((unsigned)f2bf(v.y) << 16);
        o.y = (unsigned)f2bf(v.z) | ((unsigned)f2bf(v.w) << 16);
        xb4[i] = o;
    } else if (i < NX4 + 2 * 32768) {
        const int j = i - NX4;
        const int which = j >> 15;  // 0 -> layer1, 1 -> layer2
        const int jj = j & 32767;
        const int n = jj >> 8;
        const int k = jj & 255;
        const float* Wl = which ? W2l : W1l;
        const float* Wr = which ? W2r : W1r;
        const float w = (k < 128) ? Wl[k * 128 + n] : Wr[(k - 128) * 128 + n];
        (which ? Bt2 : Bt1)[jj] = f2bf(w);
    }
}

// One wave per bin: coalesced uint4 exclusive scan over the 256 columns.
__global__ __launch_bounds__(256) void scanB_kernel(unsigned* __restrict__ G,
                                                    int nbins,
                                                    int* __restrict__ tot) {
    const int wave = threadIdx.x >> 6;
    const int lane = threadIdx.x & 63;
    const int bin = blockIdx.x * 4 + wave;
    if (bin >= nbins) return;
    unsigned* p = G + (size_t)bin * NBLK + lane * 4;
    uint4 v = *(uint4*)p;
    const unsigned s = v.x + v.y + v.z + v.w;
    unsigned sc = s;
#pragma unroll
    for (int off = 1; off < 64; off <<= 1) {
        const unsigned u = (unsigned)__shfl_up((int)sc, off, 64);
        if (lane >= off) sc += u;
    }
    const unsigned excl = sc - s;
    uint4 w;
    w.x = excl;
    w.y = excl + v.x;
    w.z = excl + v.x + v.y;
    w.w = excl + v.x + v.y + v.z;
    *(uint4*)p = w;
    if (lane == 63) tot[bin] = (int)(excl + s);
}

// Single-block exclusive scan of tot -> tile_base[0..nbins].
__global__ __launch_bounds__(1024) void scanC_kernel(
    const int* __restrict__ tot, int nbins, int* __restrict__ tile_base) {
    __shared__ int part[1024];
    const int t = threadIdx.x;
    const int chunk = (nbins + 1023) >> 10;
    const int lo = min(t * chunk, nbins);
    const int hi = min(lo + chunk, nbins);
    int s = 0;
    for (int i = lo; i < hi; ++i) s += tot[i];
    part[t] = s;
    __syncthreads();
    for (int off = 1; off < 1024; off <<= 1) {
        int add = (t >= off) ? part[t - off] : 0;
        __syncthreads();
        part[t] += add;
        __syncthreads();
    }
    int excl = (t == 0) ? 0 : part[t - 1];
    for (int i = lo; i < hi; ++i) {
        tile_base[i] = excl;
        excl += tot[i];
    }
    if (t == 1023) tile_base[nbins] = part[1023];
}

// Rank replay + scatter into tile-grouped csr.
__global__ __launch_bounds__(256) void fillB_kernel(
    const int* __restrict__ src, const int* __restrict__ dst, int E,
    const unsigned* __restrict__ G, const int* __restrict__ tile_base,
    unsigned* __restrict__ csr, int nbins) {
    __shared__ int rank[2048];
    __shared__ int base[2048];
    const int t = threadIdx.x;
    for (int i = t; i < nbins; i += 256) {
        rank[i] = 0;
        base[i] = tile_base[i] + (int)G[(size_t)i * NBLK + blockIdx.x];
    }
    __syncthreads();
    const int per = (E + NBLK - 1) / NBLK;
    const int lo = blockIdx.x * per;
    const int hi = min(lo + per, E);
    for (int i = lo + t; i < hi; i += 256) {
        const int d = dst[i];
        const int bin = d >> 5;
        const int r = atomicAdd(&rank[bin], 1);
        csr[base[bin] + r] = (unsigned)src[i] | ((unsigned)d << 16);
    }
}

// One block per tile: in-LDS 32-bin counting sort of the tile's csr range
// (row-grouped, in place) + invL_g = 1/max(deg,1). Runs once, reused by both
// sage layers. nE > CAP (never at E/nbins ~512): skip reorder, still correct.
__global__ __launch_bounds__(256) void sortT_kernel(unsigned* __restrict__ csr,
                                                    const int* __restrict__
                                                        tile_base,
                                                    float* __restrict__ invL_g,
                                                    int N) {
    __shared__ unsigned sortedE[CAP];
    __shared__ int rowcnt[32];
    __shared__ int rowofs[32];
    const int b = blockIdx.x;
    const int i0 = b * 32;
    const int t = threadIdx.x;
    const int rs0 = tile_base[b];
    const int re0 = tile_base[b + 1];
    const int nE = re0 - rs0;

    if (t < 32) rowcnt[t] = 0;
    __syncthreads();
    for (int i = t; i < nE; i += 256)
        atomicAdd(&rowcnt[(csr[rs0 + i] >> 16) & 31], 1);
    __syncthreads();
    if (t < 32) {
        const int v = rowcnt[t];
        if (i0 + t < N) invL_g[i0 + t] = 1.0f / fmaxf((float)v, 1.0f);
        int s = v;
#pragma unroll
        for (int off = 1; off < 32; off <<= 1) {
            const int u = __shfl_up(s, off, 32);
            if ((t & 31) >= off) s += u;
        }
        rowofs[t] = s - v;
    }
    __syncthreads();
    if (nE <= CAP) {
        for (int i = t; i < nE; i += 256) {
            const unsigned p = csr[rs0 + i];
            const int k = atomicAdd(&rowofs[(p >> 16) & 31], 1);
            sortedE[k] = p;
        }
        __syncthreads();
        for (int i = t; i < nE; i += 256) csr[rs0 + i] = sortedE[i];
    }
}

// Fused: segmented gather (16-lane groups x uint4, contiguous edge ranges,
// R0 loop shape) -> fp32 acc into LDS -> MFMA dual GEMM (mean at A-frag
// build). HEAD folds the Linear(128,1).
template <bool HEAD>
__global__ __launch_bounds__(256, 2) void sage_kernel(
    const unsigned short* __restrict__ xb, const unsigned* __restrict__ csr,
    const int* __restrict__ tile_base, const float* __restrict__ invL_g,
    const unsigned short* __restrict__ Bt,  // [128 n][256 k] bf16
    const float* __restrict__ bl, const float* __restrict__ Wout,
    const float* __restrict__ bout, unsigned short* __restrict__ hb_out,
    float* __restrict__ out, int N) {
    __shared__ float aggL[32 * LSTR];
    __shared__ float invL[32];
    __shared__ float redH[64];

    const int b = blockIdx.x;
    const int i0 = b * 32;
    const int t = threadIdx.x;
    const int g = t >> 4;       // 16 gather groups of 16 lanes
    const int l16 = t & 15;
    const int c8 = l16 << 3;    // 8 bf16 channels per lane

    for (int i = t; i < 32 * LSTR; i += 256) aggL[i] = 0.f;
    if (t < 32) invL[t] = (i0 + t < N) ? invL_g[i0 + t] : 1.0f;
    __syncthreads();

    // ---- segmented edge-parallel aggregation over row-sorted csr ----
    const int rs0 = tile_base[b];
    const int re0 = tile_base[b + 1];
    const int nE = re0 - rs0;
    int e = rs0 + ((nE * g) >> 4);
    const int ee = rs0 + ((nE * (g + 1)) >> 4);

    float a[8];
#pragma unroll
    for (int j = 0; j < 8; ++j) a[j] = 0.f;
    int cur = (e < ee) ? (int)(csr[e] >> 16) - i0 : -1;

    auto ld = [&](unsigned p) -> uint4 {
        return *(const uint4*)(xb + (size_t)(p & 0xffffu) * D + c8);
    };
    auto step = [&](unsigned p, const uint4& u) {
        const int r = (int)(p >> 16) - i0;
        if (r != cur) {
            float* q = aggL + cur * LSTR + c8;
#pragma unroll
            for (int m = 0; m < 8; ++m) atomicAdd(q + m, a[m]);
#pragma unroll
            for (int m = 0; m < 8; ++m) a[m] = 0.f;
            cur = r;
        }
        a[0] += __uint_as_float(u.x << 16);
        a[1] += __uint_as_float(u.x & 0xffff0000u);
        a[2] += __uint_as_float(u.y << 16);
        a[3] += __uint_as_float(u.y & 0xffff0000u);
        a[4] += __uint_as_float(u.z << 16);
        a[5] += __uint_as_float(u.z & 0xffff0000u);
        a[6] += __uint_as_float(u.w << 16);
        a[7] += __uint_as_float(u.w & 0xffff0000u);
    };

    while (e + 8 <= ee) {
        const unsigned p0 = csr[e + 0], p1 = csr[e + 1];
        const unsigned p2 = csr[e + 2], p3 = csr[e + 3];
        const unsigned p4 = csr[e + 4], p5 = csr[e + 5];
        const unsigned p6 = csr[e + 6], p7 = csr[e + 7];
        const uint4 v0 = ld(p0), v1 = ld(p1), v2 = ld(p2), v3 = ld(p3),
                    v4 = ld(p4), v5 = ld(p5), v6 = ld(p6), v7 = ld(p7);
        step(p0, v0); step(p1, v1); step(p2, v2); step(p3, v3);
        step(p4, v4); step(p5, v5); step(p6, v6); step(p7, v7);
        e += 8;
    }
    while (e < ee) {
        const unsigned p = csr[e];
        step(p, ld(p));
        ++e;
    }
    if (cur >= 0) {
        float* q = aggL + cur * LSTR + c8;
#pragma unroll
        for (int m = 0; m < 8; ++m) atomicAdd(q + m, a[m]);
    }
    __syncthreads();

    // ---- MFMA dual GEMM: [agg*inv | x](32x256) @ Bt^T(256x128) ----
    const int wave = t >> 6;
    const int lane = t & 63;
    const int ln = lane & 15;
    const int quad = lane >> 4;
    const int mtile = wave & 1;       // rows mtile*16..+15
    const int nt0 = (wave >> 1) * 4;  // 4 n-tiles per wave
    const int mrow = mtile * 16 + ln;
    const int gmr = i0 + mrow;
    const float inv = invL[mrow];

    f32x4 acc4[4] = {f32x4{0.f, 0.f, 0.f, 0.f}, f32x4{0.f, 0.f, 0.f, 0.f},
                     f32x4{0.f, 0.f, 0.f, 0.f}, f32x4{0.f, 0.f, 0.f, 0.f}};

#pragma unroll
    for (int s = 0; s < 4; ++s) {
        const int kb = s * 32 + quad * 8;
        const float* ap = aggL + mrow * LSTR + kb;
        const float4 fa = *(const float4*)ap;
        const float4 fb = *(const float4*)(ap + 4);
        const short8 aA = {(short)f2bf(fa.x * inv), (short)f2bf(fa.y * inv),
                           (short)f2bf(fa.z * inv), (short)f2bf(fa.w * inv),
                           (short)f2bf(fb.x * inv), (short)f2bf(fb.y * inv),
                           (short)f2bf(fb.z * inv), (short)f2bf(fb.w * inv)};
        short8 aX = {0, 0, 0, 0, 0, 0, 0, 0};
        if (gmr < N) aX = *(const short8*)(xb + (size_t)gmr * D + kb);
#pragma unroll
        for (int nt = 0; nt < 4; ++nt) {
            const int n = (nt0 + nt) * 16 + ln;
            const short8 b1 = *(const short8*)(Bt + n * 256 + kb);
            const short8 b2 = *(const short8*)(Bt + n * 256 + 128 + kb);
            acc4[nt] = __builtin_amdgcn_mfma_f32_16x16x32_bf16(aA, b1, acc4[nt],
                                                               0, 0, 0);
            acc4[nt] = __builtin_amdgcn_mfma_f32_16x16x32_bf16(aX, b2, acc4[nt],
                                                               0, 0, 0);
        }
    }

    // ---- epilogue: C/D layout col=lane&15, row=quad*4+reg ----
    float biasv[4], woutv[4];
#pragma unroll
    for (int nt = 0; nt < 4; ++nt) {
        const int col = (nt0 + nt) * 16 + ln;
        biasv[nt] = bl[col];
        if (HEAD) woutv[nt] = Wout[col];
    }

    if (!HEAD) {
#pragma unroll
        for (int r = 0; r < 4; ++r) {
            const int gr = i0 + mtile * 16 + quad * 4 + r;
            if (gr < N) {
#pragma unroll
                for (int nt = 0; nt < 4; ++nt) {
                    const int col = (nt0 + nt) * 16 + ln;
                    const float v = fmaxf(acc4[nt][r] + biasv[nt], 0.f);
                    hb_out[(size_t)gr * D + col] = f2bf(v);
                }
            }
        }
    } else {
        const float b0 = bout[0];
#pragma unroll
        for (int r = 0; r < 4; ++r) {
            const int row = mtile * 16 + quad * 4 + r;
            float p = 0.f;
#pragma unroll
            for (int nt = 0; nt < 4; ++nt) {
                const float v = fmaxf(acc4[nt][r] + biasv[nt], 0.f);
                p += v * woutv[nt];
            }
            p += __shfl_xor(p, 1);
            p += __shfl_xor(p, 2);
            p += __shfl_xor(p, 4);
            p += __shfl_xor(p, 8);
            if (ln == 0) redH[row * 2 + (wave >> 1)] = p;
        }
        __syncthreads();
        if (t < 32) {
            const int gr = i0 + t;
            if (gr < N) out[gr] = redH[t * 2] + redH[t * 2 + 1] + b0;
        }
    }
}

extern "C" void kernel_launch(void* const* d_in, const int* in_sizes, int n_in,
                              void* d_out, int out_size, void* d_ws,
                              size_t ws_size, hipStream_t stream) {
    const float* x = (const float*)d_in[0];
    const int* ei = (const int*)d_in[1];
    const float* W1l = (const float*)d_in[2];
    const float* b1l = (const float*)d_in[3];
    const float* W1r = (const float*)d_in[4];
    const float* W2l = (const float*)d_in[5];
    const float* b2l = (const float*)d_in[6];
    const float* W2r = (const float*)d_in[7];
    const float* Wout = (const float*)d_in[8];
    const float* bout = (const float*)d_in[9];

    const int N = in_sizes[0] / D;
    const int E = in_sizes[1] / 2;
    const int* src = ei;
    const int* dst = ei + E;

    const int nbins = (N + 31) / 32;  // 32-row tiles (= sage blocks), <= 2048
    const size_t Npad = (size_t)((N + 255) & ~255);
    const size_t Epad = (size_t)((E + 255) & ~255);

    int* tot = (int*)d_ws;                        // [2048]
    int* tile_base = tot + 2048;                  // [2052]
    float* invL_g = (float*)(tile_base + 2052);   // [Npad]
    unsigned* G = (unsigned*)(invL_g + Npad);     // [2048 * NBLK]
    unsigned* csr = G + (size_t)2048 * NBLK;
    unsigned short* xb = (unsigned short*)(csr + Epad);
    unsigned short* hb = xb + (size_t)N * D;
    unsigned short* Bt1 = hb + (size_t)N * D;
    unsigned short* Bt2 = Bt1 + 128 * 256;
    float* out = (float*)d_out;

    const int NX4 = N * D / 4;
    const int prep_blocks = (NX4 + 2 * 32768 + 255) / 256;

    prep_hist_kernel<<<NBLK + prep_blocks, 256, 0, stream>>>(
        x, W1l, W1r, W2l, W2r, (uint2*)xb, Bt1, Bt2, NX4, dst, E, nbins, G);
    scanB_kernel<<<(nbins + 3) / 4, 256, 0, stream>>>(G, nbins, tot);
    scanC_kernel<<<1, 1024, 0, stream>>>(tot, nbins, tile_base);
    fillB_kernel<<<NBLK, 256, 0, stream>>>(src, dst, E, G, tile_base, csr,
                                           nbins);
    sortT_kernel<<<nbins, 256, 0, stream>>>(csr, tile_base, invL_g, N);

    sage_kernel<false><<<nbins, 256, 0, stream>>>(
        xb, csr, tile_base, invL_g, Bt1, b1l, nullptr, nullptr, hb, nullptr, N);
    sage_kernel<true><<<nbins, 256, 0, stream>>>(
        hb, csr, tile_base, invL_g, Bt2, b2l, Wout, bout, nullptr, out, N);
}